// Round 9
// baseline (132.716 us; speedup 1.0000x reference)
//
#include <hip/hip_runtime.h>

typedef float f32x4 __attribute__((ext_vector_type(4)));
typedef __bf16 bf16x8 __attribute__((ext_vector_type(8)));

__device__ __forceinline__ unsigned short f2bf(float f) {
    union { float f; unsigned u; } v; v.f = f;
    return (unsigned short)((v.u + 0x8000u) >> 16);
}
// hard-sigmoid silu: x * med3(0.25x+0.5, 0, 1)
__device__ __forceinline__ float hsilu(float x) {
    return x * __builtin_amdgcn_fmed3f(__builtin_fmaf(x, 0.25f, 0.5f), 0.f, 1.f);
}
// sigma-permuted hidden: k-position t holds hidden index 16*(t&3) + (t>>2)
// (h rows are written as byte pos = 4*l15 + n -> hidden 16n+l15).
__device__ __forceinline__ int sig_hid(int t) { return 16 * (t & 3) + (t >> 2); }

// ---------------------------------------------------------------------------
// prep: blocks 0..1023 fill out=-1e9; 1024..1055 pack W->bf16 B-frags;
// 1056..1057 w2->fp8 B-frags (sigma-permuted k); 1058 w1(+b1)->fp8 B-frags
// and w3->fp8 B-frags (sigma-permuted); 1059..1062 per-batch compaction.
// ---------------------------------------------------------------------------
__global__ __launch_bounds__(256) void prep_kernel(
    const float* __restrict__ W, const float* __restrict__ w2,
    const float* __restrict__ w1, const float* __restrict__ b1,
    const float* __restrict__ w3,
    const int* __restrict__ amask, const float* __restrict__ coords,
    float* __restrict__ out, unsigned short* __restrict__ Wf,
    long long* __restrict__ w2f, long long* __restrict__ w1f,
    long long* __restrict__ w3f,
    int* __restrict__ qlc, float2* __restrict__ ccomp, int* __restrict__ Na)
{
    const int blk = blockIdx.x, tid = threadIdx.x;

    if (blk < 1024) {                       // fill out with -1e9
        const float4 v = make_float4(-1e9f, -1e9f, -1e9f, -1e9f);
        float4* o = (float4*)out + blk * 1024;
        o[tid] = v; o[256 + tid] = v; o[512 + tid] = v; o[768 + tid] = v;
        return;
    }
    if (blk < 1056) {                       // W -> bf16 B-frags
        int t = (blk - 1024) * 256 + tid;   // (nt*8+s)*64 + lane, t<8192
        int f = t >> 6, lane = t & 63;
        int nt = f >> 3, s = f & 7;
        int quad = lane >> 4, l15 = lane & 15;
        unsigned short u[8];
        #pragma unroll
        for (int j = 0; j < 8; ++j)
            u[j] = f2bf(W[(32 * s + 8 * quad + j) * 256 + 16 * nt + l15]);
        *(uint4*)(Wf + t * 8) = *(const uint4*)u;
        return;
    }
    if (blk < 1058) {                       // w2 -> fp8 B-frags, f = n2*2+s
        int t = (blk - 1056) * 256 + tid;   // t<512
        int f = t >> 6, lane = t & 63;
        int n2 = f >> 1, s = f & 1;
        int quad = lane >> 4, l15 = lane & 15;
        int d[2];
        #pragma unroll
        for (int h = 0; h < 2; ++h) {
            float v[4];
            #pragma unroll
            for (int e = 0; e < 4; ++e) {
                int tp = 32 * s + 8 * quad + 4 * h + e;
                v[e] = w2[sig_hid(tp) * 64 + 16 * n2 + l15];
            }
            int lo = __builtin_amdgcn_cvt_pk_fp8_f32(v[0], v[1], 0, false);
            d[h]   = __builtin_amdgcn_cvt_pk_fp8_f32(v[2], v[3], lo, true);
        }
        long long pk; __builtin_memcpy(&pk, d, 8);
        w2f[t] = pk;
        return;
    }
    if (blk == 1058) {                      // w1(+b1) -> fp8; w3 -> fp8
        {
            int n = tid >> 6, lane = tid & 63;
            int quad = lane >> 4, l15 = lane & 15;
            int col = 16 * n + l15;
            int d[2] = {0, 0};
            if (quad == 0) {                // only k=0..7 rows are nonzero
                float v0 = w1[0 * 64 + col], v1 = w1[1 * 64 + col];
                float v2 = w1[2 * 64 + col], v3 = w1[3 * 64 + col];
                float v4 = w1[4 * 64 + col], v5 = w1[5 * 64 + col];
                float v6 = b1[col];
                int lo = __builtin_amdgcn_cvt_pk_fp8_f32(v0, v1, 0, false);
                d[0]   = __builtin_amdgcn_cvt_pk_fp8_f32(v2, v3, lo, true);
                int l1 = __builtin_amdgcn_cvt_pk_fp8_f32(v4, v5, 0, false);
                d[1]   = __builtin_amdgcn_cvt_pk_fp8_f32(v6, 0.f, l1, true);
            }
            long long pk; __builtin_memcpy(&pk, d, 8);
            w1f[tid] = pk;
        }
        if (tid < 128) {                    // w3 -> fp8 B-frags (sigma-perm)
            int s = tid >> 6, lane = tid & 63;
            int quad = lane >> 4;
            int d[2];
            #pragma unroll
            for (int h = 0; h < 2; ++h) {
                float v[4];
                #pragma unroll
                for (int e = 0; e < 4; ++e)
                    v[e] = w3[sig_hid(32 * s + 8 * quad + 4 * h + e)];
                int lo = __builtin_amdgcn_cvt_pk_fp8_f32(v[0], v[1], 0, false);
                d[h]   = __builtin_amdgcn_cvt_pk_fp8_f32(v[2], v[3], lo, true);
            }
            long long pk; __builtin_memcpy(&pk, d, 8);
            w3f[tid] = pk;
        }
        return;
    }
    // compaction: batch b, stable order, + compacted coords
    {
        __shared__ int ssum[256];
        int b = blk - 1059;
        const int* am = amask + b * 1024;
        const float2* cg2 = (const float2*)coords + b * 1024;
        int base = tid * 4;
        int m0 = am[base + 0] != 0, m1 = am[base + 1] != 0,
            m2 = am[base + 2] != 0, m3 = am[base + 3] != 0;
        int c = m0 + m1 + m2 + m3;
        ssum[tid] = c;
        __syncthreads();
        for (int off = 1; off < 256; off <<= 1) {
            int v = (tid >= off) ? ssum[tid - off] : 0;
            __syncthreads();
            ssum[tid] += v;
            __syncthreads();
        }
        int pos = ssum[tid] - c;
        int* ql = qlc + b * 1024;
        float2* cc = ccomp + b * 1024;
        if (m0) { ql[pos] = base + 0; cc[pos] = cg2[base + 0]; pos++; }
        if (m1) { ql[pos] = base + 1; cc[pos] = cg2[base + 1]; pos++; }
        if (m2) { ql[pos] = base + 2; cc[pos] = cg2[base + 2]; pos++; }
        if (m3) { ql[pos] = base + 3; cc[pos] = cg2[base + 3]; pos++; }
        if (tid == 255) Na[b] = ssum[255];
    }
}

// ---------------------------------------------------------------------------
// qw: compacted qW = q[qlc] @ W via bf16 MFMA; also emits compacted q (bf16).
// ---------------------------------------------------------------------------
__global__ __launch_bounds__(256) void qw_mfma_kernel(
    const float* __restrict__ q, const unsigned short* __restrict__ Wf,
    const int* __restrict__ qlc, const int* __restrict__ Na,
    unsigned short* __restrict__ qWc, unsigned short* __restrict__ qc)
{
    const int bb = blockIdx.y, iq = blockIdx.x;
    const int nb = Na[bb];
    if (iq * 16 >= nb) return;

    __shared__ unsigned char qs[16 * 512];
    const int tid = threadIdx.x;
    const int lane = tid & 63, wv = tid >> 6;
    const int l15 = lane & 15, quad = lane >> 4;

    #pragma unroll
    for (int it = 0; it < 4; ++it) {
        int s = tid + it * 256;
        int row = s >> 6, c64 = s & 63;
        int g = qlc[(bb << 10) + min(iq * 16 + row, nb - 1)];  // clamped gather
        float4 v = ((const float4*)q)[(size_t)((bb << 10) + g) * 64 + c64];
        ushort4 u = make_ushort4(f2bf(v.x), f2bf(v.y), f2bf(v.z), f2bf(v.w));
        int off = row * 512 + (((c64 >> 1) ^ (row & 7)) << 4) + ((c64 & 1) << 3);
        *(ushort4*)(qs + off) = u;
        ((ushort4*)qc)[(size_t)((bb << 10) + iq * 16 + row) * 64 + c64] = u;
    }
    __syncthreads();

    bf16x8 a[8];
    #pragma unroll
    for (int s = 0; s < 8; ++s)
        a[s] = *(const bf16x8*)(qs + l15 * 512 + ((((s << 2) + quad) ^ (l15 & 7)) << 4));

    f32x4 acc[4];
    #pragma unroll
    for (int n = 0; n < 4; ++n) acc[n] = (f32x4){0.f, 0.f, 0.f, 0.f};
    const uint4* wf = (const uint4*)Wf;
    #pragma unroll
    for (int s = 0; s < 8; ++s) {
        #pragma unroll
        for (int n = 0; n < 4; ++n) {
            int nt = wv * 4 + n;
            uint4 braw = wf[(nt * 8 + s) * 64 + lane];
            acc[n] = __builtin_amdgcn_mfma_f32_16x16x32_bf16(
                a[s], __builtin_bit_cast(bf16x8, braw), acc[n], 0, 0, 0);
        }
    }
    #pragma unroll
    for (int n = 0; n < 4; ++n)
        #pragma unroll
        for (int r = 0; r < 4; ++r) {
            int row = iq * 16 + quad * 4 + r;
            int col = (wv * 4 + n) * 16 + l15;
            qWc[(size_t)((bb << 10) + row) * 256 + col] = f2bf(acc[n][r]);
        }
}

// ---------------------------------------------------------------------------
// edge: persistent blocks over the exact compacted tile list (R6 structure).
// Per tile: stage qWc/qc (bf16, XOR-swizzled) + fp8 features (h1s row pad);
// sync A; bilinear bf16 MFMA (K split over waves); layer1 fp8 MFMA -> silu
// -> h1 fp8; sync B; layer2 fp8 MFMA -> silu -> h2 fp8 (same rows); sync C;
// layer3 fp8 MFMA (w3 replicated across cols) -> gs; sync D; combine+store.
// All LDS producer->consumer pairs cross a __syncthreads (round-5 lesson).
// ---------------------------------------------------------------------------
__global__ __launch_bounds__(256, 4) void edge_head_kernel(
    const unsigned short* __restrict__ qWc, const unsigned short* __restrict__ qc,
    const long long* __restrict__ w2f, const long long* __restrict__ w1f,
    const long long* __restrict__ w3f, const float2* __restrict__ ccomp,
    const int* __restrict__ qlc, const int* __restrict__ Na,
    const float* __restrict__ b2, const float* __restrict__ b3,
    const float* __restrict__ bias, float* __restrict__ out)
{
    __shared__ unsigned char qWs[16 * 512];
    __shared__ unsigned char qks[16 * 512];
    __shared__ __align__(16) unsigned char h1s[256 * 72];  // 64B data + 8B feat pad
    __shared__ float bilp[4 * 272];                        // 4 waves x 16x17
    __shared__ float gs[256];

    const int tid  = threadIdx.x;
    const int lane = tid & 63;
    const int wv   = tid >> 6;
    const int l15  = lane & 15;
    const int quad = lane >> 4;

    // per-block constants
    long long w2frag[8], w1frag[4], w3frag[2];
    #pragma unroll
    for (int f = 0; f < 8; ++f) w2frag[f] = w2f[f * 64 + lane];
    #pragma unroll
    for (int n = 0; n < 4; ++n) w1frag[n] = w1f[n * 64 + lane];
    #pragma unroll
    for (int s = 0; s < 2; ++s) w3frag[s] = w3f[s * 64 + lane];
    float b2c[4];
    #pragma unroll
    for (int n = 0; n < 4; ++n) b2c[n] = b2[16 * n + l15];
    const float c0 = b3[0] + bias[0];

    int nt[4], off[5];
    off[0] = 0;
    #pragma unroll
    for (int b = 0; b < 4; ++b) {
        int nb = Na[b];
        nt[b] = (nb + 15) >> 4;
        off[b + 1] = off[b] + nt[b] * nt[b];
    }
    const int T = off[4];

    for (int t = blockIdx.x; t < T; t += gridDim.x) {
        int bb = 0;
        while (bb < 3 && t >= off[bb + 1]) bb++;
        int loc = t - off[bb];
        int ntb = nt[bb];
        int iq = loc / ntb, ik = loc - iq * ntb;
        int nb = Na[bb];

        // ---- stage (16B chunks, XOR-swizzled) + fp8 features ----
        {
            const uint4* qWg = (const uint4*)qWc + (size_t)((bb << 10) + iq * 16) * 32;
            const uint4* qkg = (const uint4*)qc  + (size_t)((bb << 10) + ik * 16) * 32;
            #pragma unroll
            for (int it = 0; it < 2; ++it) {
                int s = tid + it * 256;       // 16B chunk: row*32 + c16
                int row = s >> 5, c16 = s & 31;
                int o = row * 512 + ((c16 ^ (row & 7)) << 4);
                *(uint4*)(qWs + o) = qWg[s];
                *(uint4*)(qks + o) = qkg[s];
            }
            // features for pair p = tid (ql = p&15, kl = p>>4); clamped reads
            int qa = min(iq * 16 + (tid & 15), nb - 1);
            int ka = min(ik * 16 + (tid >> 4), nb - 1);
            float2 cq = ccomp[(bb << 10) + qa];
            float2 ck = ccomp[(bb << 10) + ka];
            float dx = cq.x - ck.x, dy = cq.y - ck.y;
            float dist2 = dx * dx + dy * dy;
            float dist = sqrtf(dist2 + 1e-8f);
            bool mz = (fabsf(dx) < 1e-6f) && (fabsf(dy) < 1e-6f);
            float dxs = mz ? 1e-6f : dx;
            float dys = mz ? 1e-6f : dy;
            float rinv = __builtin_amdgcn_rsqf(dxs * dxs + dys * dys);
            float sv = dys * rinv, cv = dxs * rinv;
            int a  = __builtin_amdgcn_cvt_pk_fp8_f32(dx, dy, 0, false);
            int d0 = __builtin_amdgcn_cvt_pk_fp8_f32(dist, dist2, a, true);
            int b  = __builtin_amdgcn_cvt_pk_fp8_f32(sv, cv, 0, false);
            int d1 = b | 0x00380000;          // bytes [sv, cv, 1.0fp8, 0]
            *(int2*)(h1s + tid * 72 + 64) = make_int2(d0, d1);
        }
        __syncthreads();   // A: staging + features visible

        // ---- bilinear: wave wv does K-steps 2wv, 2wv+1 ----
        {
            f32x4 accb = {0.f, 0.f, 0.f, 0.f};
            #pragma unroll
            for (int i = 0; i < 2; ++i) {
                int s = 2 * wv + i;
                int o = l15 * 512 + ((((s << 2) + quad) ^ (l15 & 7)) << 4);
                bf16x8 av = *(const bf16x8*)(qWs + o);
                bf16x8 bv = *(const bf16x8*)(qks + o);
                accb = __builtin_amdgcn_mfma_f32_16x16x32_bf16(av, bv, accb, 0, 0, 0);
            }
            #pragma unroll
            for (int r = 0; r < 4; ++r)
                bilp[wv * 272 + (quad * 4 + r) * 17 + l15] = accb[r];
        }

        // ---- layer1 MFMA (K=32, features in k=0..7) -> silu -> h1 fp8 ----
        #pragma unroll
        for (int m = 0; m < 4; ++m) {
            int mt = wv * 4 + m;
            int2 fv = *(const int2*)(h1s + (mt * 16 + l15) * 72 + 64);
            long long af = __builtin_bit_cast(long long, fv);
            f32x4 h[4];
            #pragma unroll
            for (int n = 0; n < 4; ++n)
                h[n] = __builtin_amdgcn_mfma_f32_16x16x32_fp8_fp8(
                    af, w1frag[n], (f32x4){0.f, 0.f, 0.f, 0.f}, 0, 0, 0);
            #pragma unroll
            for (int r = 0; r < 4; ++r) {
                float s0 = hsilu(h[0][r]), s1 = hsilu(h[1][r]);
                float s2 = hsilu(h[2][r]), s3 = hsilu(h[3][r]);
                int lo = __builtin_amdgcn_cvt_pk_fp8_f32(s0, s1, 0, false);
                int dw = __builtin_amdgcn_cvt_pk_fp8_f32(s2, s3, lo, true);
                *(int*)(h1s + (mt * 16 + quad * 4 + r) * 72 + l15 * 4) = dw;
            }
        }
        __syncthreads();   // B: h1 visible

        // ---- layer2 MFMA -> silu -> h2 fp8 (overwrite same rows) ----
        #pragma unroll
        for (int tt = 0; tt < 4; ++tt) {
            int tm = wv * 4 + tt;
            unsigned rb = (unsigned)(tm * 16 + l15) * 72 + 8 * quad;
            long long a0 = __builtin_bit_cast(long long, *(const int2*)(h1s + rb));
            long long a1 = __builtin_bit_cast(long long, *(const int2*)(h1s + rb + 32));
            f32x4 acc[4];
            #pragma unroll
            for (int n = 0; n < 4; ++n)
                acc[n] = (f32x4){b2c[n], b2c[n], b2c[n], b2c[n]};
            #pragma unroll
            for (int n = 0; n < 4; ++n) {
                acc[n] = __builtin_amdgcn_mfma_f32_16x16x32_fp8_fp8(a0, w2frag[n * 2 + 0], acc[n], 0, 0, 0);
                acc[n] = __builtin_amdgcn_mfma_f32_16x16x32_fp8_fp8(a1, w2frag[n * 2 + 1], acc[n], 0, 0, 0);
            }
            #pragma unroll
            for (int r = 0; r < 4; ++r) {
                float s0 = hsilu(acc[0][r]), s1 = hsilu(acc[1][r]);
                float s2 = hsilu(acc[2][r]), s3 = hsilu(acc[3][r]);
                int lo = __builtin_amdgcn_cvt_pk_fp8_f32(s0, s1, 0, false);
                int dw = __builtin_amdgcn_cvt_pk_fp8_f32(s2, s3, lo, true);
                *(int*)(h1s + (tm * 16 + quad * 4 + r) * 72 + l15 * 4) = dw;
            }
        }
        __syncthreads();   // C: h2 visible (mandatory before layer3 reads)

        // ---- layer3 MFMA (w3 replicated across cols) -> gs ----
        #pragma unroll
        for (int tt = 0; tt < 4; ++tt) {
            int tm = wv * 4 + tt;
            unsigned rb = (unsigned)(tm * 16 + l15) * 72 + 8 * quad;
            long long g0 = __builtin_bit_cast(long long, *(const int2*)(h1s + rb));
            long long g1 = __builtin_bit_cast(long long, *(const int2*)(h1s + rb + 32));
            f32x4 gacc = __builtin_amdgcn_mfma_f32_16x16x32_fp8_fp8(
                g0, w3frag[0], (f32x4){0.f, 0.f, 0.f, 0.f}, 0, 0, 0);
            gacc = __builtin_amdgcn_mfma_f32_16x16x32_fp8_fp8(g1, w3frag[1], gacc, 0, 0, 0);
            if (l15 == 0) {
                #pragma unroll
                for (int r = 0; r < 4; ++r)
                    gs[tm * 16 + quad * 4 + r] = gacc[r] + c0;
            }
        }
        __syncthreads();   // D: gs + bilp visible

        // ---- combine + diag + scatter store ----
        {
            int fq = tid >> 4, fk = tid & 15;
            float logit = bilp[0 * 272 + fq * 17 + fk] + bilp[1 * 272 + fq * 17 + fk]
                        + bilp[2 * 272 + fq * 17 + fk] + bilp[3 * 272 + fq * 17 + fk]
                        + gs[fk * 16 + fq];
            bool valid = (iq * 16 + fq < nb) && (ik * 16 + fk < nb);
            int qi = qlc[(bb << 10) + min(iq * 16 + fq, nb - 1)];
            int ki = qlc[(bb << 10) + min(ik * 16 + fk, nb - 1)];
            if (qi == ki) logit = 0.f;
            if (valid) out[(size_t)((bb << 10) + qi) * 1024 + ki] = logit;
        }
    }
}

extern "C" void kernel_launch(void* const* d_in, const int* in_sizes, int n_in,
                              void* d_out, int out_size, void* d_ws, size_t ws_size,
                              hipStream_t stream) {
    const float* q      = (const float*)d_in[0];   // [4,1024,256]
    const float* coords = (const float*)d_in[1];   // [4,1024,2]
    const int*   amask  = (const int*)d_in[2];     // [4,1024]
    const float* W      = (const float*)d_in[3];   // [256,256]
    const float* w1     = (const float*)d_in[4];   // [6,64]
    const float* b1     = (const float*)d_in[5];   // [64]
    const float* w2     = (const float*)d_in[6];   // [64,64]
    const float* b2     = (const float*)d_in[7];   // [64]
    const float* w3     = (const float*)d_in[8];   // [64,1]
    const float* b3     = (const float*)d_in[9];   // [1]
    const float* bias   = (const float*)d_in[10];  // [1]
    float* out = (float*)d_out;

    char* p = (char*)d_ws;
    unsigned short* qWc  = (unsigned short*)p;  p += 4096 * 256 * 2;  // 2 MB
    unsigned short* qc   = (unsigned short*)p;  p += 4096 * 256 * 2;  // 2 MB
    unsigned short* Wf   = (unsigned short*)p;  p += 8192 * 8 * 2;    // 128 KB
    long long*      w2f  = (long long*)p;       p += 512 * 8;         // 4 KB
    long long*      w1f  = (long long*)p;       p += 256 * 8;         // 2 KB
    long long*      w3f  = (long long*)p;       p += 128 * 8;         // 1 KB
    int*            qlc  = (int*)p;             p += 4096 * 4;        // 16 KB
    float2*         ccomp= (float2*)p;          p += 4096 * 8;        // 32 KB
    int*            Na   = (int*)p;

    prep_kernel<<<dim3(1063), dim3(256), 0, stream>>>(
        W, w2, w1, b1, w3, amask, coords, out, Wf, w2f, w1f, w3f, qlc, ccomp, Na);
    qw_mfma_kernel<<<dim3(64, 4), dim3(256), 0, stream>>>(
        q, Wf, qlc, Na, qWc, qc);
    edge_head_kernel<<<dim3(1024), dim3(256), 0, stream>>>(
        qWc, qc, w2f, w1f, w3f, ccomp, qlc, Na, b2, b3, bias, out);
}